// Round 3
// baseline (46.213 us; speedup 1.0000x reference)
//
#include <hip/hip_runtime.h>
#include <hip/hip_bf16.h>

// CSPN step: out[b,y,x] = sum_{i,j} gw[b, i*3+j, y+1, x+1] * src[y+1-i, x+1-j]
// src = h0 for center tap (i=j=1), hn otherwise; zero outside [0,H)x[0,W).
// Branch-free, 8 px/thread, XCD-swizzled so batch b lives on XCD b.

constexpr int B = 8;
constexpr int H = 352;
constexpr int W = 1216;
constexpr int HP = H + 2;            // 354
constexpr int WP = W + 2;            // 1218
constexpr int CPR = W / 8;           // 152 chunks per row
constexpr size_t PLANE = (size_t)HP * WP;
constexpr int NBLK = B * H * CPR / 256;   // 1672 blocks, divisible by 8

typedef float f4  __attribute__((ext_vector_type(4)));
typedef float f4a __attribute__((ext_vector_type(4), aligned(4)));  // 4B-aligned vec load

__global__ __launch_bounds__(256) void cspn8_kernel(
    const float* __restrict__ gw,   // [B, 9, HP, WP]
    const float* __restrict__ hn,   // [B, 1, H, W]
    const float* __restrict__ h0,   // [B, 1, H, W]
    float* __restrict__ out)        // [B, 1, H, W]
{
    // XCD swizzle: hw assigns dispatch-index d -> XCD d%8; remap so each XCD
    // gets a contiguous logical range = exactly one batch image (209 blocks).
    int bid = blockIdx.x;
    int swz = (bid & 7) * (NBLK / 8) + (bid >> 3);
    int tid = swz * 256 + threadIdx.x;

    int cx = tid % CPR;
    int t2 = tid / CPR;
    int y  = t2 % H;
    int b  = t2 / H;
    int x0 = cx * 8;

    const float* hnb = hn + (size_t)b * H * W;
    const float* h0p = h0 + (size_t)b * H * W + (size_t)y * W + x0;
    const float* gwp = gw + (size_t)b * 9 * PLANE + (size_t)(y + 1) * WP + x0;
    float* outp = out + (size_t)b * H * W + (size_t)y * W + x0;

    // hn rows i=0..2: row yy = y+1-i, cols x0-1 .. x0+8 (10 values), masked OOB.
    float r[3][10];
    int lo = (cx == 0)       ? x0    : x0 - 1;
    int hi = (cx == CPR - 1) ? W - 1 : x0 + 8;
#pragma unroll
    for (int i = 0; i < 3; ++i) {
        int yy = y + 1 - i;
        bool ok = (i == 1) | ((i == 0) ? (y < H - 1) : (y > 0));
        int ay = ok ? yy : y;                       // clamped valid row
        const float* rp = hnb + (size_t)ay * W;
        float s0 = rp[lo];
        f4 v0 = *reinterpret_cast<const f4*>(rp + x0);        // 16B aligned
        f4 v1 = *reinterpret_cast<const f4*>(rp + x0 + 4);    // 16B aligned
        float s1 = rp[hi];
        r[i][0] = (ok & (cx > 0)) ? s0 : 0.f;
#pragma unroll
        for (int k = 0; k < 4; ++k) r[i][1 + k] = ok ? v0[k] : 0.f;
#pragma unroll
        for (int k = 0; k < 4; ++k) r[i][5 + k] = ok ? v1[k] : 0.f;
        r[i][9] = (ok & (cx < CPR - 1)) ? s1 : 0.f;
    }

    // h0 center row (always in-bounds)
    f4 c0 = *reinterpret_cast<const f4*>(h0p);
    f4 c1 = *reinterpret_cast<const f4*>(h0p + 4);
    float cc[8];
#pragma unroll
    for (int k = 0; k < 4; ++k) { cc[k] = c0[k]; cc[4 + k] = c1[k]; }

    float a[8];
#pragma unroll
    for (int p = 0; p < 8; ++p) a[p] = 0.f;

#pragma unroll
    for (int i = 0; i < 3; ++i) {
#pragma unroll
        for (int j = 0; j < 3; ++j) {
            const int t = i * 3 + j;
            const float* gt = gwp + (size_t)t * PLANE;
            // gw cols x0+1 .. x0+8 (always in-bounds: gw is pre-padded)
            f4a gA = __builtin_nontemporal_load(reinterpret_cast<const f4a*>(gt + 1));
            f4a gB = __builtin_nontemporal_load(reinterpret_cast<const f4a*>(gt + 5));
#pragma unroll
            for (int p = 0; p < 8; ++p) {
                float g = (p < 4) ? gA[p] : gB[p - 4];
                float s = (t == 4) ? cc[p] : r[i][p + 2 - j];
                a[p] = fmaf(g, s, a[p]);
            }
        }
    }

    f4 o0, o1;
#pragma unroll
    for (int k = 0; k < 4; ++k) { o0[k] = a[k]; o1[k] = a[4 + k]; }
    __builtin_nontemporal_store(o0, reinterpret_cast<f4*>(outp));
    __builtin_nontemporal_store(o1, reinterpret_cast<f4*>(outp + 4));
}

extern "C" void kernel_launch(void* const* d_in, const int* in_sizes, int n_in,
                              void* d_out, int out_size, void* d_ws, size_t ws_size,
                              hipStream_t stream) {
    const float* gw = (const float*)d_in[0];
    const float* hn = (const float*)d_in[1];
    const float* h0 = (const float*)d_in[2];
    float* out = (float*)d_out;

    cspn8_kernel<<<NBLK, 256, 0, stream>>>(gw, hn, h0, out);
}

// Round 4
// 37.328 us; speedup vs baseline: 1.2380x; 1.2380x over previous
//
#include <hip/hip_runtime.h>
#include <hip/hip_bf16.h>

// CSPN step: out[b,y,x] = sum_{i,j} gw[b, i*3+j, y+1, x+1] * src[y+1-i, x+1-j]
// src = h0 for center tap (i=j=1), hn otherwise; zero outside [0,H)x[0,W).
// 4 px/thread phased so gw loads are 8B-aligned dwordx2; plain loads; edge px
// {0,1213,1214,1215} handled by one compact thread per row.

constexpr int B = 8;
constexpr int H = 352;
constexpr int W = 1216;
constexpr int HP = H + 2;            // 354
constexpr int WP = W + 2;            // 1218
constexpr int CPR = 304;             // 303 interior chunks + 1 edge chunk
constexpr size_t PLANE = (size_t)HP * WP;

typedef float f2 __attribute__((ext_vector_type(2)));

__global__ __launch_bounds__(256) void cspn_r3_kernel(
    const float* __restrict__ gw,   // [B, 9, HP, WP]
    const float* __restrict__ hn,   // [B, 1, H, W]
    const float* __restrict__ h0,   // [B, 1, H, W]
    float* __restrict__ out)        // [B, 1, H, W]
{
    int tid = blockIdx.x * 256 + threadIdx.x;
    int cx = tid % CPR;
    int t2 = tid / CPR;
    int y  = t2 % H;
    int b  = t2 / H;

    const float* hnb = hn + (size_t)b * H * W;
    const float* h0r = h0 + (size_t)b * H * W + (size_t)y * W;
    const float* gwr = gw + (size_t)b * 9 * PLANE + (size_t)(y + 1) * WP;
    float* outr = out + (size_t)b * H * W + (size_t)y * W;

    if (cx < 303) {
        int x0 = 4 * cx + 1;              // out px x0..x0+3, px 1..1212

        // hn rows i=0..2: row yy = y+1-i, cols x0-1 .. x0+4 (even start -> f2 x3)
        float r[3][6];
#pragma unroll
        for (int i = 0; i < 3; ++i) {
            bool ok = (i == 1) | ((i == 0) ? (y < H - 1) : (y > 0));
            int ay = (i == 0) ? ((y < H - 1) ? y + 1 : y)
                   : (i == 2) ? ((y > 0) ? y - 1 : y) : y;
            const float* rp = hnb + (size_t)ay * W;
            f2 v0 = *reinterpret_cast<const f2*>(rp + x0 - 1);
            f2 v1 = *reinterpret_cast<const f2*>(rp + x0 + 1);
            f2 v2 = *reinterpret_cast<const f2*>(rp + x0 + 3);
            float m = ok ? 1.f : 0.f;
            r[i][0] = v0[0] * m; r[i][1] = v0[1] * m;
            r[i][2] = v1[0] * m; r[i][3] = v1[1] * m;
            r[i][4] = v2[0] * m; r[i][5] = v2[1] * m;
        }

        // h0 cols x0..x0+3 (x0 odd): scalar + f2 + scalar
        float cc[4];
        cc[0] = h0r[x0];
        f2 cm = *reinterpret_cast<const f2*>(h0r + x0 + 1);
        cc[1] = cm[0]; cc[2] = cm[1];
        cc[3] = h0r[x0 + 3];

        float acc[4] = {0.f, 0.f, 0.f, 0.f};
#pragma unroll
        for (int i = 0; i < 3; ++i) {
#pragma unroll
            for (int j = 0; j < 3; ++j) {
                const int t = i * 3 + j;
                const float* gt = gwr + (size_t)t * PLANE + x0 + 1;   // even col
                f2 g01 = *reinterpret_cast<const f2*>(gt);
                f2 g23 = *reinterpret_cast<const f2*>(gt + 2);
                float g[4] = {g01[0], g01[1], g23[0], g23[1]};
#pragma unroll
                for (int p = 0; p < 4; ++p) {
                    float s = (t == 4) ? cc[p] : r[i][p + 2 - j];
                    acc[p] = fmaf(g[p], s, acc[p]);
                }
            }
        }

        outr[x0] = acc[0];
        f2 om; om[0] = acc[1]; om[1] = acc[2];
        *reinterpret_cast<f2*>(outr + x0 + 1) = om;
        outr[x0 + 3] = acc[3];
    } else {
        // Edge pixels: x in {0, 1213, 1214, 1215}
        const float* h0b = h0r - (size_t)y * W;   // batch base
#pragma unroll
        for (int e = 0; e < 4; ++e) {
            int x = (e == 0) ? 0 : 1212 + e;
            float acc = 0.f;
#pragma unroll
            for (int i = 0; i < 3; ++i) {
                int yy = y + 1 - i;
                bool yin = (yy >= 0) & (yy < H);
#pragma unroll
                for (int j = 0; j < 3; ++j) {
                    const int t = i * 3 + j;
                    int xx = x + 1 - j;
                    bool in = yin & (xx >= 0) & (xx < W);
                    float s = 0.f;
                    if (in) {
                        const float* src = (t == 4) ? h0b : hnb;
                        s = src[(size_t)yy * W + xx];
                    }
                    acc = fmaf(gwr[(size_t)t * PLANE + x + 1], s, acc);
                }
            }
            outr[x] = acc;
        }
    }
}

extern "C" void kernel_launch(void* const* d_in, const int* in_sizes, int n_in,
                              void* d_out, int out_size, void* d_ws, size_t ws_size,
                              hipStream_t stream) {
    const float* gw = (const float*)d_in[0];
    const float* hn = (const float*)d_in[1];
    const float* h0 = (const float*)d_in[2];
    float* out = (float*)d_out;

    constexpr int total = B * H * CPR;       // 856064 threads
    constexpr int block = 256;
    constexpr int grid = total / block;      // 3344 exact
    cspn_r3_kernel<<<grid, block, 0, stream>>>(gw, hn, h0, out);
}